// Round 3
// baseline (1481.625 us; speedup 1.0000x reference)
//
#include <hip/hip_runtime.h>

// GAT layer: N=100000 nodes, E=1600000 edges, 4 heads, D_in=128, D_out=32.
// All float tensors detected bf16 (round-2 evidence: FETCH==bf16 H_in size,
// absmax == 1 bf16 ULP); edge_index int64. Detection kept for safety, but
// each dtype path is now its OWN kernel (early-exit on flag mismatch) so the
// hot bf16 GEMM gets clean codegen — round-2's dual-path kernel ran at 75 GB/s
// (0.9% HBM) with VALUBusy 7%: codegen pathology, not a bandwidth limit.

typedef __attribute__((ext_vector_type(8))) short short8_t;
typedef __attribute__((ext_vector_type(4))) float float4v;

static __device__ inline float bf2f(unsigned short u) {
    return __uint_as_float(((unsigned int)u) << 16);
}
static __device__ inline unsigned short f2bf(float f) {
    unsigned int u = __float_as_uint(f);
    return (unsigned short)((u + 0x7fffu + ((u >> 16) & 1u)) >> 16);
}

// ---------------- K0: dtype detection (see round-1 notes).
__global__ __launch_bounds__(256) void k_detect(const unsigned int* __restrict__ hwords,
                                                const unsigned int* __restrict__ ewords,
                                                int* __restrict__ flags) {
    __shared__ int s_bf, s_zero;
    if (threadIdx.x == 0) { s_bf = 0; s_zero = 0; }
    __syncthreads();
    int c = 0;
    for (int i = threadIdx.x; i < 1024; i += 256) {
        unsigned int e = (hwords[i] >> 7) & 0xFFu;
        c += (e >= 88 && e <= 140) ? 1 : 0;
    }
    atomicAdd(&s_bf, c);
    int z = 0;
    for (int i = threadIdx.x; i < 64; i += 256) z += (ewords[2 * i + 1] == 0u) ? 1 : 0;
    atomicAdd(&s_zero, z);
    __syncthreads();
    if (threadIdx.x == 0) {
        flags[0] = (s_bf >= 700) ? 1 : 0;   // bf16 ~1024, f32 ~210
        flags[1] = (s_zero >= 32) ? 1 : 0;  // int64 -> odd words zero
    }
}

// ---------------- K0b: normalize edge_index to clamped int32 [2E]
__global__ void k_cvt_ei(const int* __restrict__ raw, const int* __restrict__ flags,
                         int* __restrict__ ei32, int twoE, int nmax) {
    int i = blockIdx.x * 256 + threadIdx.x;
    if (i >= twoE) return;
    int v = flags[1] ? raw[2 * (size_t)i] : raw[i];
    v = v < 0 ? 0 : (v >= nmax ? nmax - 1 : v);
    ei32[i] = v;
}

// ---------------- K1 (bf16): Hw[n][c] = sum_k H[n][k]*W[c][k], c = h*32+o.
// 128 nodes/block, 4 waves; W (128x128 bf16 = 32KB) staged once into LDS with
// padded rows (136 shorts = 272B, 16B-aligned). A-frags direct from global
// (lane m reads its node row; lines fully consumed). MFMA 16x16x32:
// A[m=lane&15][k=quad*8+j], B[n=lane&15][k=quad*8+j], C/D col=lane&15,
// row=quad*4+reg. Each store instr writes 4 full 64B lines.
__global__ __launch_bounds__(256) void k_hw_bf16(const unsigned short* __restrict__ Hin,
                                                 const unsigned short* __restrict__ Wt,
                                                 const int* __restrict__ flags,
                                                 float* __restrict__ Hw, int nnodes) {
    if (flags[0] == 0) return;  // wrong dtype world: dead dispatch
    __shared__ __align__(16) unsigned short Wl[128 * 136];

    // stage W coalesced: 2048 x uint4
    const uint4* wsrc = (const uint4*)Wt;
    for (int i = threadIdx.x; i < 2048; i += 256) {
        int r = i >> 4, c8 = i & 15;
        *(uint4*)&Wl[r * 136 + c8 * 8] = wsrc[i];
    }
    __syncthreads();

    int wave = threadIdx.x >> 6;
    int lane = threadIdx.x & 63;
    int mrow = lane & 15;
    int quad = lane >> 4;

    for (int half = 0; half < 2; ++half) {
        int nbase = blockIdx.x * 128 + (wave * 2 + half) * 16;
        if (nbase >= nnodes) return;
        int anode = nbase + mrow;
        int nclamp = anode < nnodes ? anode : nnodes - 1;

        float4v acc[8] = {};
        const short8_t* Ap = (const short8_t*)(Hin + (size_t)nclamp * 128 + quad * 8);
        for (int kc = 0; kc < 4; ++kc) {
            short8_t a = Ap[kc * 4];  // H[node][kc*32 + quad*8 ..+8]
            for (int t = 0; t < 8; ++t) {
                short8_t b = *(const short8_t*)&Wl[(t * 16 + mrow) * 136 + kc * 32 + quad * 8];
                acc[t] = __builtin_amdgcn_mfma_f32_16x16x32_bf16(a, b, acc[t], 0, 0, 0);
            }
        }
        for (int t = 0; t < 8; ++t)
            for (int r = 0; r < 4; ++r) {
                int nrow = nbase + quad * 4 + r;
                if (nrow < nnodes)
                    Hw[(size_t)nrow * 128 + t * 16 + mrow] = acc[t][r];
            }
    }
}

// f32 fallback path (exact VALU dots; dead dispatch in bf16 world)
__global__ __launch_bounds__(256) void k_hw_f32(const float* __restrict__ Hf,
                                                const float* __restrict__ Wf,
                                                const int* __restrict__ flags,
                                                float* __restrict__ Hw, int nnodes) {
    if (flags[0] != 0) return;
    int nb = blockIdx.x * 64;
    for (int idx = threadIdx.x; idx < 64 * 128; idx += 256) {
        int node = nb + (idx >> 7);
        if (node >= nnodes) continue;
        int o = idx & 127;
        const float4v* h4 = (const float4v*)(Hf + (size_t)node * 128);
        const float4v* w4 = (const float4v*)(Wf + (size_t)o * 128);
        float s0 = 0.f, s1 = 0.f, s2 = 0.f, s3 = 0.f;
        for (int k = 0; k < 32; ++k) {
            float4v a = h4[k], b = w4[k];
            s0 += a[0] * b[0]; s1 += a[1] * b[1];
            s2 += a[2] * b[2]; s3 += a[3] * b[3];
        }
        Hw[(size_t)node * 128 + o] = (s0 + s1) + (s2 + s3);
    }
}

// ---------------- K1b: s_src/s_tgt dots
__global__ __launch_bounds__(256) void k_scores(const float* __restrict__ Hw,
                                                const void* __restrict__ Asrc_,
                                                const void* __restrict__ Atgt_,
                                                const int* __restrict__ flags,
                                                float* __restrict__ s_src,
                                                float* __restrict__ s_tgt, int nnodes) {
    __shared__ float As[128], At[128];
    bool isbf = flags[0] != 0;
    if (threadIdx.x < 128) {
        if (isbf) {
            As[threadIdx.x] = bf2f(((const unsigned short*)Asrc_)[threadIdx.x]);
            At[threadIdx.x] = bf2f(((const unsigned short*)Atgt_)[threadIdx.x]);
        } else {
            As[threadIdx.x] = ((const float*)Asrc_)[threadIdx.x];
            At[threadIdx.x] = ((const float*)Atgt_)[threadIdx.x];
        }
    }
    __syncthreads();
    int gi = blockIdx.x * 256 + threadIdx.x;
    int n = gi >> 2, h = gi & 3;
    if (n >= nnodes) return;
    const float* hw = Hw + (size_t)n * 128 + h * 32;
    float a = 0.f, b = 0.f;
    for (int o = 0; o < 32; ++o) {
        float v = hw[o];
        a += v * As[h * 32 + o];
        b += v * At[h * 32 + o];
    }
    s_src[n * 4 + h] = a;
    s_tgt[n * 4 + h] = b;
}

// ---------------- K2: in-degree histogram
__global__ void k_deg(const int* __restrict__ ei32, int* __restrict__ deg, int E) {
    int i = blockIdx.x * 256 + threadIdx.x;
    if (i < E) atomicAdd(&deg[ei32[E + i]], 1);
}

// ---------------- scan helpers
__device__ inline int block_excl_scan(int v) {
    __shared__ int wsum[8];
    int lane = threadIdx.x & 63, w = threadIdx.x >> 6;
    int inc = v;
    for (int d = 1; d < 64; d <<= 1) {
        int t = __shfl_up(inc, d, 64);
        if (lane >= d) inc += t;
    }
    if (lane == 63) wsum[w] = inc;
    __syncthreads();
    int base = 0;
    for (int i = 0; i < w; ++i) base += wsum[i];
    __syncthreads();
    return base + inc - v;
}

__global__ __launch_bounds__(256) void k_blocksum(const int* __restrict__ deg,
                                                  int* __restrict__ part, int n) {
    int i = blockIdx.x * 256 + threadIdx.x;
    int v = (i < n) ? deg[i] : 0;
    int e = block_excl_scan(v);
    if (threadIdx.x == 255) part[blockIdx.x] = e + v;
}

__global__ __launch_bounds__(512) void k_scanpart(const int* __restrict__ part,
                                                  int* __restrict__ psum, int nb) {
    int v = ((int)threadIdx.x < nb) ? part[threadIdx.x] : 0;
    int e = block_excl_scan(v);
    if ((int)threadIdx.x < nb) psum[threadIdx.x] = e;
}

__global__ __launch_bounds__(256) void k_offsets(const int* __restrict__ deg,
                                                 const int* __restrict__ psum,
                                                 int* __restrict__ offs,
                                                 int* __restrict__ cursor, int n) {
    int i = blockIdx.x * 256 + threadIdx.x;
    int v = (i < n) ? deg[i] : 0;
    int e = block_excl_scan(v) + psum[blockIdx.x];
    if (i < n) {
        offs[i] = e;
        cursor[i] = e;
        if (i == n - 1) offs[n] = e + v;
    }
}

// ---------------- K4: scatter edges into CSR
__global__ void k_fill(const int* __restrict__ ei32, int* __restrict__ cursor,
                       int* __restrict__ csr, int E) {
    int i = blockIdx.x * 256 + threadIdx.x;
    if (i < E) {
        int t = ei32[E + i];
        int slot = atomicAdd(&cursor[t], 1);
        csr[slot] = ei32[i];
    }
}

// ---------------- K5: per-node softmax + aggregation + ELU (bf16 out)
__global__ __launch_bounds__(256) void k_aggr_bf16(const int* __restrict__ offs,
                                                   const int* __restrict__ csr,
                                                   const float* __restrict__ s_src,
                                                   const float* __restrict__ s_tgt,
                                                   const float* __restrict__ Hw,
                                                   const int* __restrict__ flags,
                                                   unsigned short* __restrict__ out,
                                                   int nnodes) {
    if (flags[0] == 0) return;
    int wave = threadIdx.x >> 6, lane = threadIdx.x & 63;
    int n = blockIdx.x * 4 + wave;
    if (n >= nnodes) return;
    int off = offs[n];
    int deg = offs[n + 1] - off;

    const float4v* ss4 = (const float4v*)s_src;
    float4v st = ((const float4v*)s_tgt)[n];

    float4v se = {0.f, 0.f, 0.f, 0.f};
    for (int j = lane; j < deg; j += 64) {
        int src = csr[off + j];
        float4v ss = ss4[src];
        for (int c = 0; c < 4; ++c) {
            float x = ss[c] + st[c];
            x = fminf(fmaxf(x, 0.2f * x), 60.f);
            se[c] += __expf(x);
        }
    }
    for (int d = 1; d < 64; d <<= 1)
        for (int c = 0; c < 4; ++c) se[c] += __shfl_xor(se[c], d, 64);

    int hsel = (lane >> 5) & 1;
    float st0 = hsel ? st[1] : st[0];
    float st1 = hsel ? st[3] : st[2];
    float s0 = hsel ? se[1] : se[0];
    float s1 = hsel ? se[3] : se[2];
    float inv0 = s0 > 0.f ? 1.0f / s0 : 0.f;
    float inv1 = s1 > 0.f ? 1.0f / s1 : 0.f;

    float acc0 = 0.f, acc1 = 0.f;
    for (int base = 0; base < deg; base += 64) {
        int cnt = min(64, deg - base);
        int mysrc = (base + lane < deg) ? csr[off + base + lane] : 0;
        for (int jj = 0; jj < cnt; ++jj) {
            int src = __shfl(mysrc, jj, 64);
            float4v ss = ss4[src];
            float e0 = (hsel ? ss[1] : ss[0]) + st0;
            float e1 = (hsel ? ss[3] : ss[2]) + st1;
            e0 = fminf(fmaxf(e0, 0.2f * e0), 60.f);
            e1 = fminf(fmaxf(e1, 0.2f * e1), 60.f);
            float w0 = __expf(e0), w1 = __expf(e1);
            const float* hwrow = Hw + (size_t)src * 128;
            acc0 += w0 * hwrow[lane];
            acc1 += w1 * hwrow[64 + lane];
        }
    }
    acc0 *= inv0;
    acc1 *= inv1;
    acc0 = acc0 > 0.f ? acc0 : __expf(acc0) - 1.0f;
    acc1 = acc1 > 0.f ? acc1 : __expf(acc1) - 1.0f;

    int o = lane & 31;
    int h0 = lane >> 5, h1 = 2 + h0;
    out[(size_t)h0 * nnodes * 32 + (size_t)n * 32 + o] = f2bf(acc0);
    out[(size_t)h1 * nnodes * 32 + (size_t)n * 32 + o] = f2bf(acc1);
}

// f32-output variant (dead in bf16 world)
__global__ __launch_bounds__(256) void k_aggr_f32(const int* __restrict__ offs,
                                                  const int* __restrict__ csr,
                                                  const float* __restrict__ s_src,
                                                  const float* __restrict__ s_tgt,
                                                  const float* __restrict__ Hw,
                                                  const int* __restrict__ flags,
                                                  float* __restrict__ out, int nnodes) {
    if (flags[0] != 0) return;
    int wave = threadIdx.x >> 6, lane = threadIdx.x & 63;
    int n = blockIdx.x * 4 + wave;
    if (n >= nnodes) return;
    int off = offs[n];
    int deg = offs[n + 1] - off;

    const float4v* ss4 = (const float4v*)s_src;
    float4v st = ((const float4v*)s_tgt)[n];

    float4v se = {0.f, 0.f, 0.f, 0.f};
    for (int j = lane; j < deg; j += 64) {
        int src = csr[off + j];
        float4v ss = ss4[src];
        for (int c = 0; c < 4; ++c) {
            float x = ss[c] + st[c];
            x = fminf(fmaxf(x, 0.2f * x), 60.f);
            se[c] += __expf(x);
        }
    }
    for (int d = 1; d < 64; d <<= 1)
        for (int c = 0; c < 4; ++c) se[c] += __shfl_xor(se[c], d, 64);

    int hsel = (lane >> 5) & 1;
    float st0 = hsel ? st[1] : st[0];
    float st1 = hsel ? st[3] : st[2];
    float s0 = hsel ? se[1] : se[0];
    float s1 = hsel ? se[3] : se[2];
    float inv0 = s0 > 0.f ? 1.0f / s0 : 0.f;
    float inv1 = s1 > 0.f ? 1.0f / s1 : 0.f;

    float acc0 = 0.f, acc1 = 0.f;
    for (int base = 0; base < deg; base += 64) {
        int cnt = min(64, deg - base);
        int mysrc = (base + lane < deg) ? csr[off + base + lane] : 0;
        for (int jj = 0; jj < cnt; ++jj) {
            int src = __shfl(mysrc, jj, 64);
            float4v ss = ss4[src];
            float e0 = (hsel ? ss[1] : ss[0]) + st0;
            float e1 = (hsel ? ss[3] : ss[2]) + st1;
            e0 = fminf(fmaxf(e0, 0.2f * e0), 60.f);
            e1 = fminf(fmaxf(e1, 0.2f * e1), 60.f);
            float w0 = __expf(e0), w1 = __expf(e1);
            const float* hwrow = Hw + (size_t)src * 128;
            acc0 += w0 * hwrow[lane];
            acc1 += w1 * hwrow[64 + lane];
        }
    }
    acc0 *= inv0;
    acc1 *= inv1;
    acc0 = acc0 > 0.f ? acc0 : __expf(acc0) - 1.0f;
    acc1 = acc1 > 0.f ? acc1 : __expf(acc1) - 1.0f;

    int o = lane & 31;
    int h0 = lane >> 5, h1 = 2 + h0;
    out[(size_t)h0 * nnodes * 32 + (size_t)n * 32 + o] = acc0;
    out[(size_t)h1 * nnodes * 32 + (size_t)n * 32 + o] = acc1;
}

extern "C" void kernel_launch(void* const* d_in, const int* in_sizes, int n_in,
                              void* d_out, int out_size, void* d_ws, size_t ws_size,
                              hipStream_t stream) {
    const void* Hin = d_in[0];
    const int* ei_raw = (const int*)d_in[1];
    const void* W = d_in[2];
    const void* Asrc = d_in[3];
    const void* Atgt = d_in[4];
    int N = in_sizes[0] / 128;
    int E = in_sizes[1] / 2;

    char* ws = (char*)d_ws;
    size_t p = 0;
    auto alloc = [&](size_t bytes) {
        void* r = ws + p;
        p = (p + bytes + 511) & ~(size_t)511;
        return r;
    };
    float* Hw = (float*)alloc((size_t)N * 128 * 4);
    float* s_src = (float*)alloc((size_t)N * 4 * 4);
    float* s_tgt = (float*)alloc((size_t)N * 4 * 4);
    int* deg = (int*)alloc((size_t)N * 4);
    int* offs = (int*)alloc((size_t)(N + 1) * 4);
    int* cursor = (int*)alloc((size_t)N * 4);
    int* part = (int*)alloc(512 * 4);
    int* psum = (int*)alloc(512 * 4);
    int* csr = (int*)alloc((size_t)E * 4);
    int* ei32 = (int*)alloc((size_t)2 * E * 4);
    int* flags = (int*)alloc(2 * 4);

    hipMemsetAsync(deg, 0, (size_t)N * 4, stream);

    k_detect<<<dim3(1), 256, 0, stream>>>((const unsigned int*)Hin,
                                          (const unsigned int*)ei_raw, flags);
    k_cvt_ei<<<dim3((2 * E + 255) / 256), 256, 0, stream>>>(ei_raw, flags, ei32, 2 * E, N);

    k_hw_bf16<<<dim3((N + 127) / 128), 256, 0, stream>>>((const unsigned short*)Hin,
                                                         (const unsigned short*)W, flags,
                                                         Hw, N);
    k_hw_f32<<<dim3((N + 63) / 64), 256, 0, stream>>>((const float*)Hin, (const float*)W,
                                                      flags, Hw, N);
    k_scores<<<dim3((N * 4 + 255) / 256), 256, 0, stream>>>(Hw, Asrc, Atgt, flags, s_src,
                                                            s_tgt, N);
    k_deg<<<dim3((E + 255) / 256), 256, 0, stream>>>(ei32, deg, E);
    int nb = (N + 255) / 256;
    k_blocksum<<<dim3(nb), 256, 0, stream>>>(deg, part, N);
    k_scanpart<<<dim3(1), 512, 0, stream>>>(part, psum, nb);
    k_offsets<<<dim3(nb), 256, 0, stream>>>(deg, psum, offs, cursor, N);
    k_fill<<<dim3((E + 255) / 256), 256, 0, stream>>>(ei32, cursor, csr, E);
    k_aggr_bf16<<<dim3((N + 3) / 4), 256, 0, stream>>>(offs, csr, s_src, s_tgt, Hw, flags,
                                                       (unsigned short*)d_out, N);
    k_aggr_f32<<<dim3((N + 3) / 4), 256, 0, stream>>>(offs, csr, s_src, s_tgt, Hw, flags,
                                                      (float*)d_out, N);
}

// Round 4
// 519.592 us; speedup vs baseline: 2.8515x; 2.8515x over previous
//
#include <hip/hip_runtime.h>

// GAT layer: N=100000 nodes, E=1600000 edges, 4 heads, D_in=128, D_out=32.
// Round-3 evidence settled dtypes: hot dispatch was k_hw_f32's BODY
// (LDS_Block_Size=0, VGPR=84) => flags[0]==0 => float tensors are REAL f32,
// output f32 (k_aggr_f32 wrote the passing result). absmax 0.0156/0.0313 =
// bf16 half/one ULP => harness ref is bf16-rounded; inputs likely bf16-valued
// f32. GEMM now uses the bf16 SPLIT trick (hi+lo, 3 MFMAs) for f32 accuracy
// (~2^-16 rel) at MFMA speed. bf16-dtype paths kept as guarded fallbacks.

typedef __attribute__((ext_vector_type(8))) short short8_t;
typedef __attribute__((ext_vector_type(4))) float float4v;

static __device__ inline float bf2f(unsigned short u) {
    return __uint_as_float(((unsigned int)u) << 16);
}
static __device__ inline unsigned short f2bf(float f) {
    unsigned int u = __float_as_uint(f);
    return (unsigned short)((u + 0x7fffu + ((u >> 16) & 1u)) >> 16);
}
static __device__ inline void splitf(float v, unsigned short& h, unsigned short& l) {
    unsigned short hb = f2bf(v);
    h = hb;
    l = f2bf(v - bf2f(hb));  // Sterbenz: v-hi exact in f32
}

// ---------------- K0: dtype detection (flags[0]: floats-are-bf16; flags[1]: int64)
__global__ __launch_bounds__(256) void k_detect(const unsigned int* __restrict__ hwords,
                                                const unsigned int* __restrict__ ewords,
                                                int* __restrict__ flags) {
    __shared__ int s_bf, s_zero;
    if (threadIdx.x == 0) { s_bf = 0; s_zero = 0; }
    __syncthreads();
    int c = 0;
    for (int i = threadIdx.x; i < 1024; i += 256) {
        unsigned int e = (hwords[i] >> 7) & 0xFFu;
        c += (e >= 88 && e <= 140) ? 1 : 0;
    }
    atomicAdd(&s_bf, c);
    int z = 0;
    for (int i = threadIdx.x; i < 64; i += 256) z += (ewords[2 * i + 1] == 0u) ? 1 : 0;
    atomicAdd(&s_zero, z);
    __syncthreads();
    if (threadIdx.x == 0) {
        flags[0] = (s_bf >= 700) ? 1 : 0;   // bf16 ~1024, f32 ~210 (0 if bf16-valued f32)
        flags[1] = (s_zero >= 32) ? 1 : 0;  // int64 -> odd words zero
    }
}

// ---------------- K0b: normalize edge_index to clamped int32 [2E]
__global__ void k_cvt_ei(const int* __restrict__ raw, const int* __restrict__ flags,
                         int* __restrict__ ei32, int twoE, int nmax) {
    int i = blockIdx.x * 256 + threadIdx.x;
    if (i >= twoE) return;
    int v = flags[1] ? raw[2 * (size_t)i] : raw[i];
    v = v < 0 ? 0 : (v >= nmax ? nmax - 1 : v);
    ei32[i] = v;
}

// ---------------- K1 (f32 via split-bf16 MFMA): Hw[n][c] = sum_k H[n][k]*W[c][k]
// 128 nodes/block, 4 waves. W processed in two 64-row halves staged into LDS as
// (hi,lo) bf16 pairs, row stride 136 shorts (2-way bank aliasing only, 16B
// aligned). A rows loaded f32 and split in-register. 3 MFMAs/tile-step:
// Ah*Bh + Al*Bh + Ah*Bl (drop Al*Bl ~2^-16). MFMA 16x16x32 layout:
// A[m=lane&15][k=quad*8+j], B-frag lane n=lane&15 holds W[n][k], C/D
// col(lane&15)=outcol, row(quad*4+reg)=node.
__global__ __launch_bounds__(256) void k_hw_f32s(const float* __restrict__ Hf,
                                                 const float* __restrict__ Wf,
                                                 const int* __restrict__ flags,
                                                 float* __restrict__ Hw, int nnodes) {
    if (flags[0] != 0) return;  // bf16-dtype world handled by k_hw_bf16
    __shared__ __align__(16) unsigned short Wh[64 * 136];
    __shared__ __align__(16) unsigned short Wl[64 * 136];

    int wave = threadIdx.x >> 6;
    int lane = threadIdx.x & 63;
    int mrow = lane & 15;
    int quad = lane >> 4;

    const float4v* wsrc = (const float4v*)Wf;

    for (int hb = 0; hb < 2; ++hb) {
        if (hb) __syncthreads();  // drain half-0 readers before restage
        for (int i = threadIdx.x; i < 2048; i += 256) {
            int r = i >> 5;
            int c4 = (i & 31) * 4;
            float4v v = wsrc[(hb * 64 + r) * 32 + (i & 31)];
            ushort4 h4, l4;
            unsigned short hh, ll;
            splitf(v[0], hh, ll); h4.x = hh; l4.x = ll;
            splitf(v[1], hh, ll); h4.y = hh; l4.y = ll;
            splitf(v[2], hh, ll); h4.z = hh; l4.z = ll;
            splitf(v[3], hh, ll); h4.w = hh; l4.w = ll;
            *(ushort4*)&Wh[r * 136 + c4] = h4;
            *(ushort4*)&Wl[r * 136 + c4] = l4;
        }
        __syncthreads();

        for (int nh = 0; nh < 2; ++nh) {
            int nbase = blockIdx.x * 128 + (wave * 2 + nh) * 16;
            if (nbase >= nnodes) continue;  // keep barrier uniformity (barriers outside)
            int anode = nbase + mrow;
            int nclamp = anode < nnodes ? anode : nnodes - 1;
            const float* Hp = Hf + (size_t)nclamp * 128 + quad * 8;

            float4v acc[4] = {};
            for (int kc = 0; kc < 4; ++kc) {
                float4v va = *(const float4v*)(Hp + kc * 32);
                float4v vb = *(const float4v*)(Hp + kc * 32 + 4);
                short8_t ah, al;
                unsigned short hh, ll;
                splitf(va[0], hh, ll); ah[0] = (short)hh; al[0] = (short)ll;
                splitf(va[1], hh, ll); ah[1] = (short)hh; al[1] = (short)ll;
                splitf(va[2], hh, ll); ah[2] = (short)hh; al[2] = (short)ll;
                splitf(va[3], hh, ll); ah[3] = (short)hh; al[3] = (short)ll;
                splitf(vb[0], hh, ll); ah[4] = (short)hh; al[4] = (short)ll;
                splitf(vb[1], hh, ll); ah[5] = (short)hh; al[5] = (short)ll;
                splitf(vb[2], hh, ll); ah[6] = (short)hh; al[6] = (short)ll;
                splitf(vb[3], hh, ll); ah[7] = (short)hh; al[7] = (short)ll;
                for (int t = 0; t < 4; ++t) {
                    int boff = (t * 16 + mrow) * 136 + kc * 32 + quad * 8;
                    short8_t bh = *(const short8_t*)&Wh[boff];
                    short8_t bl = *(const short8_t*)&Wl[boff];
                    acc[t] = __builtin_amdgcn_mfma_f32_16x16x32_bf16(ah, bh, acc[t], 0, 0, 0);
                    acc[t] = __builtin_amdgcn_mfma_f32_16x16x32_bf16(al, bh, acc[t], 0, 0, 0);
                    acc[t] = __builtin_amdgcn_mfma_f32_16x16x32_bf16(ah, bl, acc[t], 0, 0, 0);
                }
            }
            for (int t = 0; t < 4; ++t)
                for (int r = 0; r < 4; ++r) {
                    int nrow = nbase + quad * 4 + r;
                    if (nrow < nnodes)
                        Hw[(size_t)nrow * 128 + hb * 64 + t * 16 + mrow] = acc[t][r];
                }
        }
    }
}

// bf16-dtype fallback (dead in f32 world)
__global__ __launch_bounds__(256) void k_hw_bf16(const unsigned short* __restrict__ Hin,
                                                 const unsigned short* __restrict__ Wt,
                                                 const int* __restrict__ flags,
                                                 float* __restrict__ Hw, int nnodes) {
    if (flags[0] == 0) return;
    __shared__ __align__(16) unsigned short Wlds[128 * 136];
    const uint4* wsrc = (const uint4*)Wt;
    for (int i = threadIdx.x; i < 2048; i += 256) {
        int r = i >> 4, c8 = i & 15;
        *(uint4*)&Wlds[r * 136 + c8 * 8] = wsrc[i];
    }
    __syncthreads();

    int wave = threadIdx.x >> 6;
    int lane = threadIdx.x & 63;
    int mrow = lane & 15;
    int quad = lane >> 4;

    for (int half = 0; half < 2; ++half) {
        int nbase = blockIdx.x * 128 + (wave * 2 + half) * 16;
        if (nbase >= nnodes) return;
        int anode = nbase + mrow;
        int nclamp = anode < nnodes ? anode : nnodes - 1;

        float4v acc[8] = {};
        const short8_t* Ap = (const short8_t*)(Hin + (size_t)nclamp * 128 + quad * 8);
        for (int kc = 0; kc < 4; ++kc) {
            short8_t a = Ap[kc * 4];
            for (int t = 0; t < 8; ++t) {
                short8_t b = *(const short8_t*)&Wlds[(t * 16 + mrow) * 136 + kc * 32 + quad * 8];
                acc[t] = __builtin_amdgcn_mfma_f32_16x16x32_bf16(a, b, acc[t], 0, 0, 0);
            }
        }
        for (int t = 0; t < 8; ++t)
            for (int r = 0; r < 4; ++r) {
                int nrow = nbase + quad * 4 + r;
                if (nrow < nnodes)
                    Hw[(size_t)nrow * 128 + t * 16 + mrow] = acc[t][r];
            }
    }
}

// ---------------- K1b: s_src/s_tgt dots (A vectors read per detected dtype)
__global__ __launch_bounds__(256) void k_scores(const float* __restrict__ Hw,
                                                const void* __restrict__ Asrc_,
                                                const void* __restrict__ Atgt_,
                                                const int* __restrict__ flags,
                                                float* __restrict__ s_src,
                                                float* __restrict__ s_tgt, int nnodes) {
    __shared__ float As[128], At[128];
    bool isbf = flags[0] != 0;
    if (threadIdx.x < 128) {
        if (isbf) {
            As[threadIdx.x] = bf2f(((const unsigned short*)Asrc_)[threadIdx.x]);
            At[threadIdx.x] = bf2f(((const unsigned short*)Atgt_)[threadIdx.x]);
        } else {
            As[threadIdx.x] = ((const float*)Asrc_)[threadIdx.x];
            At[threadIdx.x] = ((const float*)Atgt_)[threadIdx.x];
        }
    }
    __syncthreads();
    int gi = blockIdx.x * 256 + threadIdx.x;
    int n = gi >> 2, h = gi & 3;
    if (n >= nnodes) return;
    const float* hw = Hw + (size_t)n * 128 + h * 32;
    float a = 0.f, b = 0.f;
    for (int o = 0; o < 32; ++o) {
        float v = hw[o];
        a += v * As[h * 32 + o];
        b += v * At[h * 32 + o];
    }
    s_src[n * 4 + h] = a;
    s_tgt[n * 4 + h] = b;
}

// ---------------- K2: in-degree histogram
__global__ void k_deg(const int* __restrict__ ei32, int* __restrict__ deg, int E) {
    int i = blockIdx.x * 256 + threadIdx.x;
    if (i < E) atomicAdd(&deg[ei32[E + i]], 1);
}

// ---------------- scan helpers
__device__ inline int block_excl_scan(int v) {
    __shared__ int wsum[8];
    int lane = threadIdx.x & 63, w = threadIdx.x >> 6;
    int inc = v;
    for (int d = 1; d < 64; d <<= 1) {
        int t = __shfl_up(inc, d, 64);
        if (lane >= d) inc += t;
    }
    if (lane == 63) wsum[w] = inc;
    __syncthreads();
    int base = 0;
    for (int i = 0; i < w; ++i) base += wsum[i];
    __syncthreads();
    return base + inc - v;
}

__global__ __launch_bounds__(256) void k_blocksum(const int* __restrict__ deg,
                                                  int* __restrict__ part, int n) {
    int i = blockIdx.x * 256 + threadIdx.x;
    int v = (i < n) ? deg[i] : 0;
    int e = block_excl_scan(v);
    if (threadIdx.x == 255) part[blockIdx.x] = e + v;
}

__global__ __launch_bounds__(512) void k_scanpart(const int* __restrict__ part,
                                                  int* __restrict__ psum, int nb) {
    int v = ((int)threadIdx.x < nb) ? part[threadIdx.x] : 0;
    int e = block_excl_scan(v);
    if ((int)threadIdx.x < nb) psum[threadIdx.x] = e;
}

__global__ __launch_bounds__(256) void k_offsets(const int* __restrict__ deg,
                                                 const int* __restrict__ psum,
                                                 int* __restrict__ offs,
                                                 int* __restrict__ cursor, int n) {
    int i = blockIdx.x * 256 + threadIdx.x;
    int v = (i < n) ? deg[i] : 0;
    int e = block_excl_scan(v) + psum[blockIdx.x];
    if (i < n) {
        offs[i] = e;
        cursor[i] = e;
        if (i == n - 1) offs[n] = e + v;
    }
}

// ---------------- K4: scatter edges into CSR
__global__ void k_fill(const int* __restrict__ ei32, int* __restrict__ cursor,
                       int* __restrict__ csr, int E) {
    int i = blockIdx.x * 256 + threadIdx.x;
    if (i < E) {
        int t = ei32[E + i];
        int slot = atomicAdd(&cursor[t], 1);
        csr[slot] = ei32[i];
    }
}

// ---------------- K5: per-node softmax + aggregation + ELU (f32 out — the live path)
__global__ __launch_bounds__(256) void k_aggr_f32(const int* __restrict__ offs,
                                                  const int* __restrict__ csr,
                                                  const float* __restrict__ s_src,
                                                  const float* __restrict__ s_tgt,
                                                  const float* __restrict__ Hw,
                                                  const int* __restrict__ flags,
                                                  float* __restrict__ out, int nnodes) {
    if (flags[0] != 0) return;
    int wave = threadIdx.x >> 6, lane = threadIdx.x & 63;
    int n = blockIdx.x * 4 + wave;
    if (n >= nnodes) return;
    int off = offs[n];
    int deg = offs[n + 1] - off;

    const float4v* ss4 = (const float4v*)s_src;
    float4v st = ((const float4v*)s_tgt)[n];

    float4v se = {0.f, 0.f, 0.f, 0.f};
    for (int j = lane; j < deg; j += 64) {
        int src = csr[off + j];
        float4v ss = ss4[src];
        for (int c = 0; c < 4; ++c) {
            float x = ss[c] + st[c];
            x = fminf(fmaxf(x, 0.2f * x), 60.f);
            se[c] += __expf(x);
        }
    }
    for (int d = 1; d < 64; d <<= 1)
        for (int c = 0; c < 4; ++c) se[c] += __shfl_xor(se[c], d, 64);

    int hsel = (lane >> 5) & 1;
    float st0 = hsel ? st[1] : st[0];
    float st1 = hsel ? st[3] : st[2];
    float s0 = hsel ? se[1] : se[0];
    float s1 = hsel ? se[3] : se[2];
    float inv0 = s0 > 0.f ? 1.0f / s0 : 0.f;
    float inv1 = s1 > 0.f ? 1.0f / s1 : 0.f;

    float acc0 = 0.f, acc1 = 0.f;
    for (int base = 0; base < deg; base += 64) {
        int cnt = min(64, deg - base);
        int mysrc = (base + lane < deg) ? csr[off + base + lane] : 0;
        for (int jj = 0; jj < cnt; ++jj) {
            int src = __shfl(mysrc, jj, 64);
            float4v ss = ss4[src];
            float e0 = (hsel ? ss[1] : ss[0]) + st0;
            float e1 = (hsel ? ss[3] : ss[2]) + st1;
            e0 = fminf(fmaxf(e0, 0.2f * e0), 60.f);
            e1 = fminf(fmaxf(e1, 0.2f * e1), 60.f);
            float w0 = __expf(e0), w1 = __expf(e1);
            const float* hwrow = Hw + (size_t)src * 128;
            acc0 += w0 * hwrow[lane];
            acc1 += w1 * hwrow[64 + lane];
        }
    }
    acc0 *= inv0;
    acc1 *= inv1;
    acc0 = acc0 > 0.f ? acc0 : __expf(acc0) - 1.0f;
    acc1 = acc1 > 0.f ? acc1 : __expf(acc1) - 1.0f;

    int o = lane & 31;
    int h0 = lane >> 5, h1 = 2 + h0;
    out[(size_t)h0 * nnodes * 32 + (size_t)n * 32 + o] = acc0;
    out[(size_t)h1 * nnodes * 32 + (size_t)n * 32 + o] = acc1;
}

// bf16-out fallback (dead in f32 world)
__global__ __launch_bounds__(256) void k_aggr_bf16(const int* __restrict__ offs,
                                                   const int* __restrict__ csr,
                                                   const float* __restrict__ s_src,
                                                   const float* __restrict__ s_tgt,
                                                   const float* __restrict__ Hw,
                                                   const int* __restrict__ flags,
                                                   unsigned short* __restrict__ out,
                                                   int nnodes) {
    if (flags[0] == 0) return;
    int wave = threadIdx.x >> 6, lane = threadIdx.x & 63;
    int n = blockIdx.x * 4 + wave;
    if (n >= nnodes) return;
    int off = offs[n];
    int deg = offs[n + 1] - off;

    const float4v* ss4 = (const float4v*)s_src;
    float4v st = ((const float4v*)s_tgt)[n];

    float4v se = {0.f, 0.f, 0.f, 0.f};
    for (int j = lane; j < deg; j += 64) {
        int src = csr[off + j];
        float4v ss = ss4[src];
        for (int c = 0; c < 4; ++c) {
            float x = ss[c] + st[c];
            x = fminf(fmaxf(x, 0.2f * x), 60.f);
            se[c] += __expf(x);
        }
    }
    for (int d = 1; d < 64; d <<= 1)
        for (int c = 0; c < 4; ++c) se[c] += __shfl_xor(se[c], d, 64);

    int hsel = (lane >> 5) & 1;
    float st0 = hsel ? st[1] : st[0];
    float st1 = hsel ? st[3] : st[2];
    float s0 = hsel ? se[1] : se[0];
    float s1 = hsel ? se[3] : se[2];
    float inv0 = s0 > 0.f ? 1.0f / s0 : 0.f;
    float inv1 = s1 > 0.f ? 1.0f / s1 : 0.f;

    float acc0 = 0.f, acc1 = 0.f;
    for (int base = 0; base < deg; base += 64) {
        int cnt = min(64, deg - base);
        int mysrc = (base + lane < deg) ? csr[off + base + lane] : 0;
        for (int jj = 0; jj < cnt; ++jj) {
            int src = __shfl(mysrc, jj, 64);
            float4v ss = ss4[src];
            float e0 = (hsel ? ss[1] : ss[0]) + st0;
            float e1 = (hsel ? ss[3] : ss[2]) + st1;
            e0 = fminf(fmaxf(e0, 0.2f * e0), 60.f);
            e1 = fminf(fmaxf(e1, 0.2f * e1), 60.f);
            float w0 = __expf(e0), w1 = __expf(e1);
            const float* hwrow = Hw + (size_t)src * 128;
            acc0 += w0 * hwrow[lane];
            acc1 += w1 * hwrow[64 + lane];
        }
    }
    acc0 *= inv0;
    acc1 *= inv1;
    acc0 = acc0 > 0.f ? acc0 : __expf(acc0) - 1.0f;
    acc1 = acc1 > 0.f ? acc1 : __expf(acc1) - 1.0f;

    int o = lane & 31;
    int h0 = lane >> 5, h1 = 2 + h0;
    out[(size_t)h0 * nnodes * 32 + (size_t)n * 32 + o] = f2bf(acc0);
    out[(size_t)h1 * nnodes * 32 + (size_t)n * 32 + o] = f2bf(acc1);
}

extern "C" void kernel_launch(void* const* d_in, const int* in_sizes, int n_in,
                              void* d_out, int out_size, void* d_ws, size_t ws_size,
                              hipStream_t stream) {
    const void* Hin = d_in[0];
    const int* ei_raw = (const int*)d_in[1];
    const void* W = d_in[2];
    const void* Asrc = d_in[3];
    const void* Atgt = d_in[4];
    int N = in_sizes[0] / 128;
    int E = in_sizes[1] / 2;

    char* ws = (char*)d_ws;
    size_t p = 0;
    auto alloc = [&](size_t bytes) {
        void* r = ws + p;
        p = (p + bytes + 511) & ~(size_t)511;
        return r;
    };
    float* Hw = (float*)alloc((size_t)N * 128 * 4);
    float* s_src = (float*)alloc((size_t)N * 4 * 4);
    float* s_tgt = (float*)alloc((size_t)N * 4 * 4);
    int* deg = (int*)alloc((size_t)N * 4);
    int* offs = (int*)alloc((size_t)(N + 1) * 4);
    int* cursor = (int*)alloc((size_t)N * 4);
    int* part = (int*)alloc(512 * 4);
    int* psum = (int*)alloc(512 * 4);
    int* csr = (int*)alloc((size_t)E * 4);
    int* ei32 = (int*)alloc((size_t)2 * E * 4);
    int* flags = (int*)alloc(2 * 4);

    hipMemsetAsync(deg, 0, (size_t)N * 4, stream);

    k_detect<<<dim3(1), 256, 0, stream>>>((const unsigned int*)Hin,
                                          (const unsigned int*)ei_raw, flags);
    k_cvt_ei<<<dim3((2 * E + 255) / 256), 256, 0, stream>>>(ei_raw, flags, ei32, 2 * E, N);

    k_hw_f32s<<<dim3((N + 127) / 128), 256, 0, stream>>>((const float*)Hin, (const float*)W,
                                                         flags, Hw, N);
    k_hw_bf16<<<dim3((N + 127) / 128), 256, 0, stream>>>((const unsigned short*)Hin,
                                                         (const unsigned short*)W, flags,
                                                         Hw, N);
    k_scores<<<dim3((N * 4 + 255) / 256), 256, 0, stream>>>(Hw, Asrc, Atgt, flags, s_src,
                                                            s_tgt, N);
    k_deg<<<dim3((E + 255) / 256), 256, 0, stream>>>(ei32, deg, E);
    int nb = (N + 255) / 256;
    k_blocksum<<<dim3(nb), 256, 0, stream>>>(deg, part, N);
    k_scanpart<<<dim3(1), 512, 0, stream>>>(part, psum, nb);
    k_offsets<<<dim3(nb), 256, 0, stream>>>(deg, psum, offs, cursor, N);
    k_fill<<<dim3((E + 255) / 256), 256, 0, stream>>>(ei32, cursor, csr, E);
    k_aggr_f32<<<dim3((N + 3) / 4), 256, 0, stream>>>(offs, csr, s_src, s_tgt, Hw, flags,
                                                      (float*)d_out, N);
    k_aggr_bf16<<<dim3((N + 3) / 4), 256, 0, stream>>>(offs, csr, s_src, s_tgt, Hw, flags,
                                                       (unsigned short*)d_out, N);
}

// Round 5
// 434.559 us; speedup vs baseline: 3.4095x; 1.1957x over previous
//
#include <hip/hip_runtime.h>

// GAT layer: N=100000 nodes, E=1600000 edges, 4 heads, D_in=128, D_out=32.
// Dtypes (settled rounds 2-4): floats are f32 (bf16-valued), edge_index int64
// (flag-detected, int32 tolerated), output f32. GEMM = split-bf16 MFMA
// (hi+lo, 3 MFMAs, ~2^-16 rel). Scores fused into GEMM via v = W^T a
// (s_src = H.v_src exactly). Hw stored bf16 (halves the 819MB edge gather;
// adds <=~0.02 abs error vs 0.117 threshold). Aggregation: single-pass
// chunked softmax with LDS weight staging (exp computed once per edge).

typedef __attribute__((ext_vector_type(8))) short short8_t;
typedef __attribute__((ext_vector_type(4))) float float4v;
typedef __attribute__((ext_vector_type(2))) float float2v;

static __device__ inline float bf2f(unsigned short u) {
    return __uint_as_float(((unsigned int)u) << 16);
}
static __device__ inline unsigned short f2bf(float f) {
    unsigned int u = __float_as_uint(f);
    return (unsigned short)((u + 0x7fffu + ((u >> 16) & 1u)) >> 16);
}
static __device__ inline void splitf(float v, unsigned short& h, unsigned short& l) {
    unsigned short hb = f2bf(v);
    h = hb;
    l = f2bf(v - bf2f(hb));  // residual exact in f32
}

// ---------------- K0: int-width detection (flags[1]: int64). flags[0] kept for diag.
__global__ __launch_bounds__(256) void k_detect(const unsigned int* __restrict__ hwords,
                                                const unsigned int* __restrict__ ewords,
                                                int* __restrict__ flags) {
    __shared__ int s_bf, s_zero;
    if (threadIdx.x == 0) { s_bf = 0; s_zero = 0; }
    __syncthreads();
    int c = 0;
    for (int i = threadIdx.x; i < 1024; i += 256) {
        unsigned int e = (hwords[i] >> 7) & 0xFFu;
        c += (e >= 88 && e <= 140) ? 1 : 0;
    }
    atomicAdd(&s_bf, c);
    int z = 0;
    for (int i = threadIdx.x; i < 64; i += 256) z += (ewords[2 * i + 1] == 0u) ? 1 : 0;
    atomicAdd(&s_zero, z);
    __syncthreads();
    if (threadIdx.x == 0) {
        flags[0] = (s_bf >= 700) ? 1 : 0;
        flags[1] = (s_zero >= 32) ? 1 : 0;
    }
}

// ---------------- K0b: tgt -> clamped int32 + in-degree histogram (fused)
__global__ void k_cvt_deg(const int* __restrict__ raw, const int* __restrict__ flags,
                          int* __restrict__ tgt32, int* __restrict__ deg, int E, int nmax) {
    int i = blockIdx.x * 256 + threadIdx.x;
    if (i >= E) return;
    int t = flags[1] ? raw[2 * ((size_t)E + i)] : raw[(size_t)E + i];
    t = t < 0 ? 0 : (t >= nmax ? nmax - 1 : t);
    tgt32[i] = t;
    atomicAdd(&deg[t], 1);
}

// ---------------- K0c: v_src[h][k] = sum_o W[h][o][k]*A_src[h][o] (and v_tgt)
__global__ __launch_bounds__(256) void k_prep(const float* __restrict__ Wf,
                                              const float* __restrict__ Asrc,
                                              const float* __restrict__ Atgt,
                                              float* __restrict__ vsrc,
                                              float* __restrict__ vtgt) {
    __shared__ float As[128], At[128];
    if (threadIdx.x < 128) {
        As[threadIdx.x] = Asrc[threadIdx.x];
        At[threadIdx.x] = Atgt[threadIdx.x];
    }
    __syncthreads();
    for (int p = threadIdx.x; p < 512; p += 256) {
        int h = p >> 7, k = p & 127;
        float a = 0.f, b = 0.f;
        for (int o = 0; o < 32; ++o) {
            float w = Wf[((size_t)(h * 32 + o)) * 128 + k];
            a += w * As[h * 32 + o];
            b += w * At[h * 32 + o];
        }
        vsrc[p] = a;  // p == h*128+k
        vtgt[p] = b;
    }
}

// ---------------- K1: fused GEMM + scores (split-bf16 MFMA).
// Hwb[n][c] (bf16) = sum_k H[n][k]*W[c][k]; s_src/s_tgt via 5th tile with
// B rows 0-3 = v_src[h], 4-7 = v_tgt[h], 8-15 = 0.
// MFMA 16x16x32: A[m=lane&15][k=quad*8+j], B[n=lane&15][k], C/D col=lane&15,
// row=quad*4+reg. 128 nodes/block; W in two 64-row halves in LDS (hi/lo,
// stride 136 shorts -> only free 2-way bank aliasing, 16B aligned).
__global__ __launch_bounds__(256) void k_hw(const float* __restrict__ Hf,
                                            const float* __restrict__ Wf,
                                            const float* __restrict__ vsrc,
                                            const float* __restrict__ vtgt,
                                            unsigned short* __restrict__ Hwb,
                                            float* __restrict__ s_src,
                                            float* __restrict__ s_tgt, int nnodes) {
    __shared__ __align__(16) unsigned short Wh[64 * 136];
    __shared__ __align__(16) unsigned short Wl[64 * 136];
    __shared__ __align__(16) unsigned short Sh[16 * 136];
    __shared__ __align__(16) unsigned short Sl[16 * 136];

    int wave = threadIdx.x >> 6;
    int lane = threadIdx.x & 63;
    int mrow = lane & 15;
    int quad = lane >> 4;

    // stage score-B tile once: rows 0-3 v_src, 4-7 v_tgt, 8-15 zero
    for (int i = threadIdx.x; i < 512; i += 256) {
        int r = i >> 5, c4 = (i & 31) * 4;
        float4v v = {0.f, 0.f, 0.f, 0.f};
        if (r < 4) v = *(const float4v*)(vsrc + r * 128 + c4);
        else if (r < 8) v = *(const float4v*)(vtgt + (r - 4) * 128 + c4);
        ushort4 h4, l4;
        unsigned short hh, ll;
        splitf(v[0], hh, ll); h4.x = hh; l4.x = ll;
        splitf(v[1], hh, ll); h4.y = hh; l4.y = ll;
        splitf(v[2], hh, ll); h4.z = hh; l4.z = ll;
        splitf(v[3], hh, ll); h4.w = hh; l4.w = ll;
        *(ushort4*)&Sh[r * 136 + c4] = h4;
        *(ushort4*)&Sl[r * 136 + c4] = l4;
    }

    const float4v* wsrc = (const float4v*)Wf;

    for (int hb = 0; hb < 2; ++hb) {
        if (hb) __syncthreads();  // drain half-0 readers before restage
        for (int i = threadIdx.x; i < 2048; i += 256) {
            int r = i >> 5, c4 = (i & 31) * 4;
            float4v v = wsrc[(hb * 64 + r) * 32 + (i & 31)];
            ushort4 h4, l4;
            unsigned short hh, ll;
            splitf(v[0], hh, ll); h4.x = hh; l4.x = ll;
            splitf(v[1], hh, ll); h4.y = hh; l4.y = ll;
            splitf(v[2], hh, ll); h4.z = hh; l4.z = ll;
            splitf(v[3], hh, ll); h4.w = hh; l4.w = ll;
            *(ushort4*)&Wh[r * 136 + c4] = h4;
            *(ushort4*)&Wl[r * 136 + c4] = l4;
        }
        __syncthreads();

        for (int nh = 0; nh < 2; ++nh) {
            int nbase = blockIdx.x * 128 + (wave * 2 + nh) * 16;
            if (nbase >= nnodes) continue;  // barriers stay outside (uniform)
            int anode = nbase + mrow;
            int nclamp = anode < nnodes ? anode : nnodes - 1;
            const float* Hp = Hf + (size_t)nclamp * 128 + quad * 8;

            float4v acc[4] = {};
            float4v accS = {};
            for (int kc = 0; kc < 4; ++kc) {
                float4v va = *(const float4v*)(Hp + kc * 32);
                float4v vb = *(const float4v*)(Hp + kc * 32 + 4);
                short8_t ah, al;
                unsigned short hh, ll;
                splitf(va[0], hh, ll); ah[0] = (short)hh; al[0] = (short)ll;
                splitf(va[1], hh, ll); ah[1] = (short)hh; al[1] = (short)ll;
                splitf(va[2], hh, ll); ah[2] = (short)hh; al[2] = (short)ll;
                splitf(va[3], hh, ll); ah[3] = (short)hh; al[3] = (short)ll;
                splitf(vb[0], hh, ll); ah[4] = (short)hh; al[4] = (short)ll;
                splitf(vb[1], hh, ll); ah[5] = (short)hh; al[5] = (short)ll;
                splitf(vb[2], hh, ll); ah[6] = (short)hh; al[6] = (short)ll;
                splitf(vb[3], hh, ll); ah[7] = (short)hh; al[7] = (short)ll;
                for (int t = 0; t < 4; ++t) {
                    int boff = (t * 16 + mrow) * 136 + kc * 32 + quad * 8;
                    short8_t bh = *(const short8_t*)&Wh[boff];
                    short8_t bl = *(const short8_t*)&Wl[boff];
                    acc[t] = __builtin_amdgcn_mfma_f32_16x16x32_bf16(ah, bh, acc[t], 0, 0, 0);
                    acc[t] = __builtin_amdgcn_mfma_f32_16x16x32_bf16(al, bh, acc[t], 0, 0, 0);
                    acc[t] = __builtin_amdgcn_mfma_f32_16x16x32_bf16(ah, bl, acc[t], 0, 0, 0);
                }
                if (hb == 0) {
                    int soff = mrow * 136 + kc * 32 + quad * 8;
                    short8_t bh = *(const short8_t*)&Sh[soff];
                    short8_t bl = *(const short8_t*)&Sl[soff];
                    accS = __builtin_amdgcn_mfma_f32_16x16x32_bf16(ah, bh, accS, 0, 0, 0);
                    accS = __builtin_amdgcn_mfma_f32_16x16x32_bf16(al, bh, accS, 0, 0, 0);
                    accS = __builtin_amdgcn_mfma_f32_16x16x32_bf16(ah, bl, accS, 0, 0, 0);
                }
            }
            for (int t = 0; t < 4; ++t)
                for (int r = 0; r < 4; ++r) {
                    int nrow = nbase + quad * 4 + r;
                    if (nrow < nnodes)
                        Hwb[(size_t)nrow * 128 + hb * 64 + t * 16 + mrow] = f2bf(acc[t][r]);
                }
            if (hb == 0) {
                for (int r = 0; r < 4; ++r) {
                    int nrow = nbase + quad * 4 + r;
                    if (nrow < nnodes) {
                        if (mrow < 4) s_src[nrow * 4 + mrow] = accS[r];
                        else if (mrow < 8) s_tgt[nrow * 4 + (mrow - 4)] = accS[r];
                    }
                }
            }
        }
    }
}

// ---------------- scan helpers
__device__ inline int block_excl_scan(int v) {
    __shared__ int wsum[8];
    int lane = threadIdx.x & 63, w = threadIdx.x >> 6;
    int inc = v;
    for (int d = 1; d < 64; d <<= 1) {
        int t = __shfl_up(inc, d, 64);
        if (lane >= d) inc += t;
    }
    if (lane == 63) wsum[w] = inc;
    __syncthreads();
    int base = 0;
    for (int i = 0; i < w; ++i) base += wsum[i];
    __syncthreads();
    return base + inc - v;
}

__global__ __launch_bounds__(256) void k_blocksum(const int* __restrict__ deg,
                                                  int* __restrict__ part, int n) {
    int i = blockIdx.x * 256 + threadIdx.x;
    int v = (i < n) ? deg[i] : 0;
    int e = block_excl_scan(v);
    if (threadIdx.x == 255) part[blockIdx.x] = e + v;
}

__global__ __launch_bounds__(512) void k_scanpart(const int* __restrict__ part,
                                                  int* __restrict__ psum, int nb) {
    int v = ((int)threadIdx.x < nb) ? part[threadIdx.x] : 0;
    int e = block_excl_scan(v);
    if ((int)threadIdx.x < nb) psum[threadIdx.x] = e;
}

__global__ __launch_bounds__(256) void k_offsets(const int* __restrict__ deg,
                                                 const int* __restrict__ psum,
                                                 int* __restrict__ offs,
                                                 int* __restrict__ cursor, int n) {
    int i = blockIdx.x * 256 + threadIdx.x;
    int v = (i < n) ? deg[i] : 0;
    int e = block_excl_scan(v) + psum[blockIdx.x];
    if (i < n) {
        offs[i] = e;
        cursor[i] = e;
        if (i == n - 1) offs[n] = e + v;
    }
}

// ---------------- K4: scatter edges into CSR (src clamped from raw)
__global__ void k_fill(const int* __restrict__ raw, const int* __restrict__ tgt32,
                       const int* __restrict__ flags, int* __restrict__ cursor,
                       int* __restrict__ csr, int E, int nmax) {
    int i = blockIdx.x * 256 + threadIdx.x;
    if (i >= E) return;
    int t = tgt32[i];
    int slot = atomicAdd(&cursor[t], 1);
    int s = flags[1] ? raw[2 * (size_t)i] : raw[i];
    s = s < 0 ? 0 : (s >= nmax ? nmax - 1 : s);
    csr[slot] = s;
}

// ---------------- K5: per-node softmax + aggregation + ELU. One wave/node.
// Single pass over 64-edge chunks: lane j computes edge j's 4 exp-weights once
// (accumulating the denominator), stages to LDS; accumulation loop broadcasts
// weights from LDS. Lane loads one uint (2 bf16 cols 2*lane, 2*lane+1) per
// edge; its head h = lane>>4. Normalize + ELU once at the end.
__global__ __launch_bounds__(256) void k_aggr(const int* __restrict__ offs,
                                              const int* __restrict__ csr,
                                              const float* __restrict__ s_src,
                                              const float* __restrict__ s_tgt,
                                              const unsigned int* __restrict__ Hwb,
                                              float* __restrict__ out, int nnodes) {
    __shared__ int srcs[4][64];
    __shared__ __align__(16) float wbuf[4][64 * 4];
    int wave = threadIdx.x >> 6, lane = threadIdx.x & 63;
    int n = blockIdx.x * 4 + wave;
    if (n >= nnodes) return;
    int off = offs[n];
    int deg = offs[n + 1] - off;
    int h = lane >> 4;

    const float4v* ss4 = (const float4v*)s_src;
    float4v st = ((const float4v*)s_tgt)[n];

    float se0 = 0.f, se1 = 0.f, se2 = 0.f, se3 = 0.f;
    float acc0 = 0.f, acc1 = 0.f;

    for (int base = 0; base < deg; base += 64) {
        int cnt = min(64, deg - base);
        // previous chunk's LDS reads are in-order in the DS pipe; drain anyway
        asm volatile("s_waitcnt lgkmcnt(0)" ::: "memory");
        if (lane < cnt) {
            int s = csr[off + base + lane];
            srcs[wave][lane] = s;
            float4v ss = ss4[s];
            float4v w;
            for (int c = 0; c < 4; ++c) {
                float x = ss[c] + st[c];
                x = fminf(fmaxf(x, 0.2f * x), 60.f);  // leaky_relu + safety clamp
                w[c] = __expf(x);
            }
            se0 += w[0]; se1 += w[1]; se2 += w[2]; se3 += w[3];
            *(float4v*)&wbuf[wave][lane * 4] = w;
        }
        asm volatile("s_waitcnt lgkmcnt(0)" ::: "memory");

        int k = 0;
        for (; k + 4 <= cnt; k += 4) {
            int q0 = srcs[wave][k], q1 = srcs[wave][k + 1];
            int q2 = srcs[wave][k + 2], q3 = srcs[wave][k + 3];
            float w0 = wbuf[wave][k * 4 + h], w1 = wbuf[wave][(k + 1) * 4 + h];
            float w2 = wbuf[wave][(k + 2) * 4 + h], w3 = wbuf[wave][(k + 3) * 4 + h];
            unsigned int u0 = Hwb[(size_t)q0 * 64 + lane];
            unsigned int u1 = Hwb[(size_t)q1 * 64 + lane];
            unsigned int u2 = Hwb[(size_t)q2 * 64 + lane];
            unsigned int u3 = Hwb[(size_t)q3 * 64 + lane];
            acc0 += w0 * __uint_as_float(u0 << 16);
            acc1 += w0 * __uint_as_float(u0 & 0xffff0000u);
            acc0 += w1 * __uint_as_float(u1 << 16);
            acc1 += w1 * __uint_as_float(u1 & 0xffff0000u);
            acc0 += w2 * __uint_as_float(u2 << 16);
            acc1 += w2 * __uint_as_float(u2 & 0xffff0000u);
            acc0 += w3 * __uint_as_float(u3 << 16);
            acc1 += w3 * __uint_as_float(u3 & 0xffff0000u);
        }
        for (; k < cnt; ++k) {
            int q = srcs[wave][k];
            float w = wbuf[wave][k * 4 + h];
            unsigned int u = Hwb[(size_t)q * 64 + lane];
            acc0 += w * __uint_as_float(u << 16);
            acc1 += w * __uint_as_float(u & 0xffff0000u);
        }
    }

    for (int d = 1; d < 64; d <<= 1) {
        se0 += __shfl_xor(se0, d, 64);
        se1 += __shfl_xor(se1, d, 64);
        se2 += __shfl_xor(se2, d, 64);
        se3 += __shfl_xor(se3, d, 64);
    }
    float seh = (h == 0) ? se0 : (h == 1) ? se1 : (h == 2) ? se2 : se3;
    float inv = seh > 0.f ? 1.0f / seh : 0.f;
    acc0 *= inv;
    acc1 *= inv;
    acc0 = acc0 > 0.f ? acc0 : __expf(acc0) - 1.0f;  // elu
    acc1 = acc1 > 0.f ? acc1 : __expf(acc1) - 1.0f;

    int o = (2 * lane) & 31;  // even; h == (2*lane)>>5 == lane>>4
    float2v val = {acc0, acc1};
    *(float2v*)&out[(((size_t)h * nnodes + n) * 32) + o] = val;
}

extern "C" void kernel_launch(void* const* d_in, const int* in_sizes, int n_in,
                              void* d_out, int out_size, void* d_ws, size_t ws_size,
                              hipStream_t stream) {
    const float* Hin = (const float*)d_in[0];
    const int* ei_raw = (const int*)d_in[1];
    const float* W = (const float*)d_in[2];
    const float* Asrc = (const float*)d_in[3];
    const float* Atgt = (const float*)d_in[4];
    int N = in_sizes[0] / 128;
    int E = in_sizes[1] / 2;

    char* ws = (char*)d_ws;
    size_t p = 0;
    auto alloc = [&](size_t bytes) {
        void* r = ws + p;
        p = (p + bytes + 511) & ~(size_t)511;
        return r;
    };
    unsigned short* Hwb = (unsigned short*)alloc((size_t)N * 128 * 2);  // 25.6 MB bf16
    float* s_src = (float*)alloc((size_t)N * 4 * 4);
    float* s_tgt = (float*)alloc((size_t)N * 4 * 4);
    int* deg = (int*)alloc((size_t)N * 4);
    int* offs = (int*)alloc((size_t)(N + 1) * 4);
    int* cursor = (int*)alloc((size_t)N * 4);
    int* part = (int*)alloc(512 * 4);
    int* psum = (int*)alloc(512 * 4);
    int* csr = (int*)alloc((size_t)E * 4);
    int* tgt32 = (int*)alloc((size_t)E * 4);
    float* vsrc = (float*)alloc(512 * 4);
    float* vtgt = (float*)alloc(512 * 4);
    int* flags = (int*)alloc(2 * 4);

    hipMemsetAsync(deg, 0, (size_t)N * 4, stream);

    k_detect<<<dim3(1), 256, 0, stream>>>((const unsigned int*)Hin,
                                          (const unsigned int*)ei_raw, flags);
    k_cvt_deg<<<dim3((E + 255) / 256), 256, 0, stream>>>(ei_raw, flags, tgt32, deg, E, N);
    k_prep<<<dim3(1), 256, 0, stream>>>(W, Asrc, Atgt, vsrc, vtgt);
    k_hw<<<dim3((N + 127) / 128), 256, 0, stream>>>(Hin, W, vsrc, vtgt, Hwb, s_src, s_tgt, N);

    int nb = (N + 255) / 256;
    k_blocksum<<<dim3(nb), 256, 0, stream>>>(deg, part, N);
    k_scanpart<<<dim3(1), 512, 0, stream>>>(part, psum, nb);
    k_offsets<<<dim3(nb), 256, 0, stream>>>(deg, psum, offs, cursor, N);
    k_fill<<<dim3((E + 255) / 256), 256, 0, stream>>>(ei_raw, tgt32, flags, cursor, csr, E, N);
    k_aggr<<<dim3((N + 3) / 4), 256, 0, stream>>>(offs, csr, s_src, s_tgt,
                                                  (const unsigned int*)Hwb, (float*)d_out, N);
}

// Round 6
// 337.123 us; speedup vs baseline: 4.3949x; 1.2890x over previous
//
#include <hip/hip_runtime.h>

// GAT layer: N=100000 nodes, E=1600000 edges, 4 heads, D_in=128, D_out=32.
// Dtypes (settled): floats f32 (bf16-valued), edge_index int64 (flag-detected),
// output f32. GEMM = split-bf16 MFMA; scores fused via v = W^T a; Hw stored
// bf16. Round-6 change: CSR build via 2-level bucket sort (LDS histograms +
// windowed scatter) replacing the atomic scatter that wrote 106MB HBM for a
// 6.4MB payload (64B line per random 4B store).

typedef __attribute__((ext_vector_type(8))) short short8_t;
typedef __attribute__((ext_vector_type(4))) float float4v;
typedef __attribute__((ext_vector_type(2))) float float2v;

static __device__ inline float bf2f(unsigned short u) {
    return __uint_as_float(((unsigned int)u) << 16);
}
static __device__ inline unsigned short f2bf(float f) {
    unsigned int u = __float_as_uint(f);
    return (unsigned short)((u + 0x7fffu + ((u >> 16) & 1u)) >> 16);
}
static __device__ inline void splitf(float v, unsigned short& h, unsigned short& l) {
    unsigned short hb = f2bf(v);
    h = hb;
    l = f2bf(v - bf2f(hb));  // residual exact in f32
}

// ---------------- K0: int-width detection (flags[1]: int64)
__global__ __launch_bounds__(256) void k_detect(const unsigned int* __restrict__ hwords,
                                                const unsigned int* __restrict__ ewords,
                                                int* __restrict__ flags) {
    __shared__ int s_bf, s_zero;
    if (threadIdx.x == 0) { s_bf = 0; s_zero = 0; }
    __syncthreads();
    int c = 0;
    for (int i = threadIdx.x; i < 1024; i += 256) {
        unsigned int e = (hwords[i] >> 7) & 0xFFu;
        c += (e >= 88 && e <= 140) ? 1 : 0;
    }
    atomicAdd(&s_bf, c);
    int z = 0;
    for (int i = threadIdx.x; i < 64; i += 256) z += (ewords[2 * i + 1] == 0u) ? 1 : 0;
    atomicAdd(&s_zero, z);
    __syncthreads();
    if (threadIdx.x == 0) {
        flags[0] = (s_bf >= 700) ? 1 : 0;
        flags[1] = (s_zero >= 32) ? 1 : 0;
    }
}

// ---------------- P1: per-block bucket histogram (bucket = tgt>>8), write tgt32.
// 16384 edges/block, 256 threads (64/thread). H[blk][b] row-major.
__global__ __launch_bounds__(256) void k_hist(const int* __restrict__ raw,
                                              const int* __restrict__ flags,
                                              int* __restrict__ tgt32, int* __restrict__ H,
                                              int E, int nmax, int NB) {
    __shared__ int h[512];
    for (int i = threadIdx.x; i < 512; i += 256) h[i] = 0;
    __syncthreads();
    bool i64 = flags[1] != 0;
    int base = blockIdx.x * 16384;
    for (int k = 0; k < 64; ++k) {
        int i = base + k * 256 + threadIdx.x;
        if (i < E) {
            int t = i64 ? raw[2 * ((size_t)E + i)] : raw[(size_t)E + i];
            t = t < 0 ? 0 : (t >= nmax ? nmax - 1 : t);
            tgt32[i] = t;
            atomicAdd(&h[t >> 8], 1);
        }
    }
    __syncthreads();
    for (int i = threadIdx.x; i < NB; i += 256) H[blockIdx.x * NB + i] = h[i];
}

// ---------------- bscan: H[blk][b] -> absolute write cursors; base[b]; offs[N]=E.
// One 1024-thread block; thread b owns bucket-column b (coalesced row access).
__global__ __launch_bounds__(1024) void k_bscan(int* __restrict__ H, int* __restrict__ base,
                                                int* __restrict__ offs, int nblkE, int NB,
                                                int N, int E) {
    __shared__ int wsum[16];
    int b = threadIdx.x;
    int run = 0;
    if (b < NB) {
        for (int blk = 0; blk < nblkE; ++blk) {
            int idx = blk * NB + b;
            int t = H[idx];
            H[idx] = run;
            run += t;
        }
    }
    // exclusive scan of run across 1024 threads
    int lane = threadIdx.x & 63, w = threadIdx.x >> 6;
    int inc = run;
    for (int d = 1; d < 64; d <<= 1) {
        int t = __shfl_up(inc, d, 64);
        if (lane >= d) inc += t;
    }
    if (lane == 63) wsum[w] = inc;
    __syncthreads();
    int wb = 0;
    for (int i = 0; i < w; ++i) wb += wsum[i];
    int e = wb + inc - run;
    if (b < NB) {
        base[b] = e;
        for (int blk = 0; blk < nblkE; ++blk) H[blk * NB + b] += e;
        if (b == NB - 1) {
            base[NB] = e + run;
            offs[N] = e + run;
        }
    }
}

// ---------------- P2: scatter (src,tgt) pairs grouped by bucket.
// LDS cursors seeded from Hoff -> per-(block,bucket) slots contiguous (~336B runs).
__global__ __launch_bounds__(256) void k_scat(const int* __restrict__ raw,
                                              const int* __restrict__ tgt32,
                                              const int* __restrict__ flags,
                                              const int* __restrict__ Hoff,
                                              uint2* __restrict__ pairs, int E, int nmax,
                                              int NB) {
    __shared__ int cnt[512];
    for (int i = threadIdx.x; i < NB; i += 256) cnt[i] = Hoff[blockIdx.x * NB + i];
    __syncthreads();
    bool i64 = flags[1] != 0;
    int base = blockIdx.x * 16384;
    for (int k = 0; k < 64; ++k) {
        int i = base + k * 256 + threadIdx.x;
        if (i < E) {
            int t = tgt32[i];
            int s = i64 ? raw[2 * (size_t)i] : raw[i];
            s = s < 0 ? 0 : (s >= nmax ? nmax - 1 : s);
            int slot = atomicAdd(&cnt[t >> 8], 1);
            uint2 p;
            p.x = (unsigned)s;
            p.y = (unsigned)t;
            pairs[slot] = p;
        }
    }
}

// ---------------- 256-thread block exclusive scan helper
__device__ inline int block_excl_scan(int v) {
    __shared__ int wsum[8];
    int lane = threadIdx.x & 63, w = threadIdx.x >> 6;
    int inc = v;
    for (int d = 1; d < 64; d <<= 1) {
        int t = __shfl_up(inc, d, 64);
        if (lane >= d) inc += t;
    }
    if (lane == 63) wsum[w] = inc;
    __syncthreads();
    int base = 0;
    for (int i = 0; i < w; ++i) base += wsum[i];
    __syncthreads();
    return base + inc - v;
}

// ---------------- P3: per-bucket local CSR build. One block per 256-node window.
// All csr writes land in the bucket's ~16KB window from one block -> L2 merges.
__global__ __launch_bounds__(256) void k_local(const uint2* __restrict__ pairs,
                                               const int* __restrict__ base,
                                               int* __restrict__ offs, int* __restrict__ csr,
                                               int N, int NB) {
    __shared__ int dcnt[256];
    __shared__ int cur[256];
    int b = blockIdx.x;
    int lo = base[b], hi = base[b + 1];
    int nodeBase = b << 8;
    dcnt[threadIdx.x] = 0;
    __syncthreads();
    for (int i = lo + threadIdx.x; i < hi; i += 256) atomicAdd(&dcnt[pairs[i].y & 255], 1);
    __syncthreads();
    int v = dcnt[threadIdx.x];
    int e = block_excl_scan(v);
    int n = nodeBase + threadIdx.x;
    if (n < N) offs[n] = lo + e;
    cur[threadIdx.x] = lo + e;
    __syncthreads();
    for (int i = lo + threadIdx.x; i < hi; i += 256) {
        uint2 p = pairs[i];
        int slot = atomicAdd(&cur[p.y & 255], 1);
        csr[slot] = (int)p.x;
    }
}

// ---------------- K0c: v_src[h][k] = sum_o W[h][o][k]*A_src[h][o] (and v_tgt)
__global__ __launch_bounds__(256) void k_prep(const float* __restrict__ Wf,
                                              const float* __restrict__ Asrc,
                                              const float* __restrict__ Atgt,
                                              float* __restrict__ vsrc,
                                              float* __restrict__ vtgt) {
    __shared__ float As[128], At[128];
    if (threadIdx.x < 128) {
        As[threadIdx.x] = Asrc[threadIdx.x];
        At[threadIdx.x] = Atgt[threadIdx.x];
    }
    __syncthreads();
    for (int p = threadIdx.x; p < 512; p += 256) {
        int h = p >> 7, k = p & 127;
        float a = 0.f, b = 0.f;
        for (int o = 0; o < 32; ++o) {
            float w = Wf[((size_t)(h * 32 + o)) * 128 + k];
            a += w * As[h * 32 + o];
            b += w * At[h * 32 + o];
        }
        vsrc[p] = a;  // p == h*128+k
        vtgt[p] = b;
    }
}

// ---------------- K1: fused GEMM + scores (split-bf16 MFMA). See round-4 notes.
__global__ __launch_bounds__(256) void k_hw(const float* __restrict__ Hf,
                                            const float* __restrict__ Wf,
                                            const float* __restrict__ vsrc,
                                            const float* __restrict__ vtgt,
                                            unsigned short* __restrict__ Hwb,
                                            float* __restrict__ s_src,
                                            float* __restrict__ s_tgt, int nnodes) {
    __shared__ __align__(16) unsigned short Wh[64 * 136];
    __shared__ __align__(16) unsigned short Wl[64 * 136];
    __shared__ __align__(16) unsigned short Sh[16 * 136];
    __shared__ __align__(16) unsigned short Sl[16 * 136];

    int wave = threadIdx.x >> 6;
    int lane = threadIdx.x & 63;
    int mrow = lane & 15;
    int quad = lane >> 4;

    for (int i = threadIdx.x; i < 512; i += 256) {
        int r = i >> 5, c4 = (i & 31) * 4;
        float4v v = {0.f, 0.f, 0.f, 0.f};
        if (r < 4) v = *(const float4v*)(vsrc + r * 128 + c4);
        else if (r < 8) v = *(const float4v*)(vtgt + (r - 4) * 128 + c4);
        ushort4 h4, l4;
        unsigned short hh, ll;
        splitf(v[0], hh, ll); h4.x = hh; l4.x = ll;
        splitf(v[1], hh, ll); h4.y = hh; l4.y = ll;
        splitf(v[2], hh, ll); h4.z = hh; l4.z = ll;
        splitf(v[3], hh, ll); h4.w = hh; l4.w = ll;
        *(ushort4*)&Sh[r * 136 + c4] = h4;
        *(ushort4*)&Sl[r * 136 + c4] = l4;
    }

    const float4v* wsrc = (const float4v*)Wf;

    for (int hb = 0; hb < 2; ++hb) {
        if (hb) __syncthreads();
        for (int i = threadIdx.x; i < 2048; i += 256) {
            int r = i >> 5, c4 = (i & 31) * 4;
            float4v v = wsrc[(hb * 64 + r) * 32 + (i & 31)];
            ushort4 h4, l4;
            unsigned short hh, ll;
            splitf(v[0], hh, ll); h4.x = hh; l4.x = ll;
            splitf(v[1], hh, ll); h4.y = hh; l4.y = ll;
            splitf(v[2], hh, ll); h4.z = hh; l4.z = ll;
            splitf(v[3], hh, ll); h4.w = hh; l4.w = ll;
            *(ushort4*)&Wh[r * 136 + c4] = h4;
            *(ushort4*)&Wl[r * 136 + c4] = l4;
        }
        __syncthreads();

        for (int nh = 0; nh < 2; ++nh) {
            int nbase = blockIdx.x * 128 + (wave * 2 + nh) * 16;
            if (nbase >= nnodes) continue;
            int anode = nbase + mrow;
            int nclamp = anode < nnodes ? anode : nnodes - 1;
            const float* Hp = Hf + (size_t)nclamp * 128 + quad * 8;

            float4v acc[4] = {};
            float4v accS = {};
            for (int kc = 0; kc < 4; ++kc) {
                float4v va = *(const float4v*)(Hp + kc * 32);
                float4v vb = *(const float4v*)(Hp + kc * 32 + 4);
                short8_t ah, al;
                unsigned short hh, ll;
                splitf(va[0], hh, ll); ah[0] = (short)hh; al[0] = (short)ll;
                splitf(va[1], hh, ll); ah[1] = (short)hh; al[1] = (short)ll;
                splitf(va[2], hh, ll); ah[2] = (short)hh; al[2] = (short)ll;
                splitf(va[3], hh, ll); ah[3] = (short)hh; al[3] = (short)ll;
                splitf(vb[0], hh, ll); ah[4] = (short)hh; al[4] = (short)ll;
                splitf(vb[1], hh, ll); ah[5] = (short)hh; al[5] = (short)ll;
                splitf(vb[2], hh, ll); ah[6] = (short)hh; al[6] = (short)ll;
                splitf(vb[3], hh, ll); ah[7] = (short)hh; al[7] = (short)ll;
                for (int t = 0; t < 4; ++t) {
                    int boff = (t * 16 + mrow) * 136 + kc * 32 + quad * 8;
                    short8_t bh = *(const short8_t*)&Wh[boff];
                    short8_t bl = *(const short8_t*)&Wl[boff];
                    acc[t] = __builtin_amdgcn_mfma_f32_16x16x32_bf16(ah, bh, acc[t], 0, 0, 0);
                    acc[t] = __builtin_amdgcn_mfma_f32_16x16x32_bf16(al, bh, acc[t], 0, 0, 0);
                    acc[t] = __builtin_amdgcn_mfma_f32_16x16x32_bf16(ah, bl, acc[t], 0, 0, 0);
                }
                if (hb == 0) {
                    int soff = mrow * 136 + kc * 32 + quad * 8;
                    short8_t bh = *(const short8_t*)&Sh[soff];
                    short8_t bl = *(const short8_t*)&Sl[soff];
                    accS = __builtin_amdgcn_mfma_f32_16x16x32_bf16(ah, bh, accS, 0, 0, 0);
                    accS = __builtin_amdgcn_mfma_f32_16x16x32_bf16(al, bh, accS, 0, 0, 0);
                    accS = __builtin_amdgcn_mfma_f32_16x16x32_bf16(ah, bl, accS, 0, 0, 0);
                }
            }
            for (int t = 0; t < 4; ++t)
                for (int r = 0; r < 4; ++r) {
                    int nrow = nbase + quad * 4 + r;
                    if (nrow < nnodes)
                        Hwb[(size_t)nrow * 128 + hb * 64 + t * 16 + mrow] = f2bf(acc[t][r]);
                }
            if (hb == 0) {
                for (int r = 0; r < 4; ++r) {
                    int nrow = nbase + quad * 4 + r;
                    if (nrow < nnodes) {
                        if (mrow < 4) s_src[nrow * 4 + mrow] = accS[r];
                        else if (mrow < 8) s_tgt[nrow * 4 + (mrow - 4)] = accS[r];
                    }
                }
            }
        }
    }
}

// ---------------- K5: per-node softmax + aggregation + ELU (unchanged from r5)
__global__ __launch_bounds__(256) void k_aggr(const int* __restrict__ offs,
                                              const int* __restrict__ csr,
                                              const float* __restrict__ s_src,
                                              const float* __restrict__ s_tgt,
                                              const unsigned int* __restrict__ Hwb,
                                              float* __restrict__ out, int nnodes) {
    __shared__ int srcs[4][64];
    __shared__ __align__(16) float wbuf[4][64 * 4];
    int wave = threadIdx.x >> 6, lane = threadIdx.x & 63;
    int n = blockIdx.x * 4 + wave;
    if (n >= nnodes) return;
    int off = offs[n];
    int deg = offs[n + 1] - off;
    int h = lane >> 4;

    const float4v* ss4 = (const float4v*)s_src;
    float4v st = ((const float4v*)s_tgt)[n];

    float se0 = 0.f, se1 = 0.f, se2 = 0.f, se3 = 0.f;
    float acc0 = 0.f, acc1 = 0.f;

    for (int base = 0; base < deg; base += 64) {
        int cnt = min(64, deg - base);
        asm volatile("s_waitcnt lgkmcnt(0)" ::: "memory");
        if (lane < cnt) {
            int s = csr[off + base + lane];
            srcs[wave][lane] = s;
            float4v ss = ss4[s];
            float4v w;
            for (int c = 0; c < 4; ++c) {
                float x = ss[c] + st[c];
                x = fminf(fmaxf(x, 0.2f * x), 60.f);
                w[c] = __expf(x);
            }
            se0 += w[0]; se1 += w[1]; se2 += w[2]; se3 += w[3];
            *(float4v*)&wbuf[wave][lane * 4] = w;
        }
        asm volatile("s_waitcnt lgkmcnt(0)" ::: "memory");

        int k = 0;
        for (; k + 4 <= cnt; k += 4) {
            int q0 = srcs[wave][k], q1 = srcs[wave][k + 1];
            int q2 = srcs[wave][k + 2], q3 = srcs[wave][k + 3];
            float w0 = wbuf[wave][k * 4 + h], w1 = wbuf[wave][(k + 1) * 4 + h];
            float w2 = wbuf[wave][(k + 2) * 4 + h], w3 = wbuf[wave][(k + 3) * 4 + h];
            unsigned int u0 = Hwb[(size_t)q0 * 64 + lane];
            unsigned int u1 = Hwb[(size_t)q1 * 64 + lane];
            unsigned int u2 = Hwb[(size_t)q2 * 64 + lane];
            unsigned int u3 = Hwb[(size_t)q3 * 64 + lane];
            acc0 += w0 * __uint_as_float(u0 << 16);
            acc1 += w0 * __uint_as_float(u0 & 0xffff0000u);
            acc0 += w1 * __uint_as_float(u1 << 16);
            acc1 += w1 * __uint_as_float(u1 & 0xffff0000u);
            acc0 += w2 * __uint_as_float(u2 << 16);
            acc1 += w2 * __uint_as_float(u2 & 0xffff0000u);
            acc0 += w3 * __uint_as_float(u3 << 16);
            acc1 += w3 * __uint_as_float(u3 & 0xffff0000u);
        }
        for (; k < cnt; ++k) {
            int q = srcs[wave][k];
            float w = wbuf[wave][k * 4 + h];
            unsigned int u = Hwb[(size_t)q * 64 + lane];
            acc0 += w * __uint_as_float(u << 16);
            acc1 += w * __uint_as_float(u & 0xffff0000u);
        }
    }

    for (int d = 1; d < 64; d <<= 1) {
        se0 += __shfl_xor(se0, d, 64);
        se1 += __shfl_xor(se1, d, 64);
        se2 += __shfl_xor(se2, d, 64);
        se3 += __shfl_xor(se3, d, 64);
    }
    float seh = (h == 0) ? se0 : (h == 1) ? se1 : (h == 2) ? se2 : se3;
    float inv = seh > 0.f ? 1.0f / seh : 0.f;
    acc0 *= inv;
    acc1 *= inv;
    acc0 = acc0 > 0.f ? acc0 : __expf(acc0) - 1.0f;
    acc1 = acc1 > 0.f ? acc1 : __expf(acc1) - 1.0f;

    int o = (2 * lane) & 31;
    float2v val = {acc0, acc1};
    *(float2v*)&out[(((size_t)h * nnodes + n) * 32) + o] = val;
}

extern "C" void kernel_launch(void* const* d_in, const int* in_sizes, int n_in,
                              void* d_out, int out_size, void* d_ws, size_t ws_size,
                              hipStream_t stream) {
    const float* Hin = (const float*)d_in[0];
    const int* ei_raw = (const int*)d_in[1];
    const float* W = (const float*)d_in[2];
    const float* Asrc = (const float*)d_in[3];
    const float* Atgt = (const float*)d_in[4];
    int N = in_sizes[0] / 128;
    int E = in_sizes[1] / 2;
    int NB = (N + 255) >> 8;        // node buckets (256 nodes each)
    int nblkE = (E + 16383) >> 14;  // edge blocks (16384 edges each)

    char* ws = (char*)d_ws;
    size_t p = 0;
    auto alloc = [&](size_t bytes) {
        void* r = ws + p;
        p = (p + bytes + 511) & ~(size_t)511;
        return r;
    };
    unsigned short* Hwb = (unsigned short*)alloc((size_t)N * 128 * 2);  // 25.6 MB
    float* s_src = (float*)alloc((size_t)N * 4 * 4);
    float* s_tgt = (float*)alloc((size_t)N * 4 * 4);
    int* offs = (int*)alloc((size_t)(N + 1) * 4);
    int* csr = (int*)alloc((size_t)E * 4);
    int* tgt32 = (int*)alloc((size_t)E * 4);
    uint2* pairs = (uint2*)alloc((size_t)E * 8);
    int* H = (int*)alloc((size_t)nblkE * NB * 4);
    int* base = (int*)alloc((size_t)(NB + 1) * 4);
    float* vsrc = (float*)alloc(512 * 4);
    float* vtgt = (float*)alloc(512 * 4);
    int* flags = (int*)alloc(2 * 4);

    k_detect<<<dim3(1), 256, 0, stream>>>((const unsigned int*)Hin,
                                          (const unsigned int*)ei_raw, flags);
    k_hist<<<dim3(nblkE), 256, 0, stream>>>(ei_raw, flags, tgt32, H, E, N, NB);
    k_bscan<<<dim3(1), 1024, 0, stream>>>(H, base, offs, nblkE, NB, N, E);
    k_scat<<<dim3(nblkE), 256, 0, stream>>>(ei_raw, tgt32, flags, H, pairs, E, N, NB);
    k_local<<<dim3(NB), 256, 0, stream>>>(pairs, base, offs, csr, N, NB);

    k_prep<<<dim3(1), 256, 0, stream>>>(W, Asrc, Atgt, vsrc, vtgt);
    k_hw<<<dim3((N + 127) / 128), 256, 0, stream>>>(Hin, W, vsrc, vtgt, Hwb, s_src, s_tgt, N);

    k_aggr<<<dim3((N + 3) / 4), 256, 0, stream>>>(offs, csr, s_src, s_tgt,
                                                  (const unsigned int*)Hwb, (float*)d_out, N);
}